// Round 6
// baseline (124.639 us; speedup 1.0000x reference)
//
#include <hip/hip_runtime.h>
#include <hip/hip_bf16.h>

#define NROWS 262144
#define B1 1024            // k1 blocks
#define RPB 256            // rows per k1 block (4 chunks of 64)
// exp(x*0.125) == exp2(x * 0.125*log2(e))
#define CL 0.18033688011112042f

typedef __attribute__((ext_vector_type(8))) short s8v;   // 8 bf16 (4 VGPRs)
typedef __attribute__((ext_vector_type(4))) float f4v;   // MFMA acc / float4

__device__ __forceinline__ ushort f2bf(float x) {        // RNE float->bf16 bits
    unsigned u = __float_as_uint(x);
    u += 0x7FFF + ((u >> 16) & 1);
    return (ushort)(u >> 16);
}

__device__ __forceinline__ float dpp_add(float x, float y_as_dpp) { return x + y_as_dpp; }

// Full wave64 sum, PURE VALU (no DS pipe): row_shr 1/2/4/8 accumulate within
// each 16-lane row, row_bcast15/31 merge rows; total lands in lane 63.
__device__ __forceinline__ float wave_rowsum_to63(float x) {
    int t;
    t = __builtin_amdgcn_update_dpp(0, __float_as_int(x), 0x111, 0xF, 0xF, true); // row_shr:1
    x += __int_as_float(t);
    t = __builtin_amdgcn_update_dpp(0, __float_as_int(x), 0x112, 0xF, 0xF, true); // row_shr:2
    x += __int_as_float(t);
    t = __builtin_amdgcn_update_dpp(0, __float_as_int(x), 0x114, 0xF, 0xF, true); // row_shr:4
    x += __int_as_float(t);
    t = __builtin_amdgcn_update_dpp(0, __float_as_int(x), 0x118, 0xF, 0xF, true); // row_shr:8
    x += __int_as_float(t);
    t = __builtin_amdgcn_update_dpp(0, __float_as_int(x), 0x142, 0xF, 0xF, true); // row_bcast15
    x += __int_as_float(t);
    t = __builtin_amdgcn_update_dpp(0, __float_as_int(x), 0x143, 0xF, 0xF, true); // row_bcast31
    x += __int_as_float(t);
    return x;   // lane 63 holds the wave-wide sum
}
__device__ __forceinline__ float rl63(float v) {
    return __uint_as_float(__builtin_amdgcn_readlane(__float_as_uint(v), 63));
}

// sum over each contiguous 16-lane group via DPP (all lanes get result)
__device__ __forceinline__ float dpp_red16(float x) {
    int t;
    t = __builtin_amdgcn_update_dpp(0, __float_as_int(x), 0xB1,  0xF, 0xF, true);
    x += __int_as_float(t);
    t = __builtin_amdgcn_update_dpp(0, __float_as_int(x), 0x4E,  0xF, 0xF, true);
    x += __int_as_float(t);
    t = __builtin_amdgcn_update_dpp(0, __float_as_int(x), 0x141, 0xF, 0xF, true);
    x += __int_as_float(t);
    t = __builtin_amdgcn_update_dpp(0, __float_as_int(x), 0x140, 0xF, 0xF, true);
    x += __int_as_float(t);
    return x;
}

// K1: 256 rows/block, 4 waves, 4 chunks of 64 rows. Wave handles 16 rows per
// chunk (lane = column). Softmax row-sums on the VALU only (DPP+readlane).
// bf16 staging into swizzled LDS (verified conflict-free), MFMA per chunk:
// wave w owns ctx tile-row cb=w for all 4 col-tiles. Q column-sums fused.
__global__ __launch_bounds__(256, 4) void k1_stats(const float* __restrict__ Q,
                                                   const float* __restrict__ K,
                                                   const float* __restrict__ V,
                                                   float* __restrict__ ctx_part,  // [B1][4096]
                                                   float* __restrict__ qs_part)   // [B1][64]
{
    const int tid  = threadIdx.x;
    const int lane = tid & 63;
    const int wid  = tid >> 6;          // 4 waves
    const size_t base = (size_t)blockIdx.x * RPB;

    __shared__ ushort kkT[4096];        // [col][row-granules], swizzled 16B granules (8 KB)
    __shared__ ushort vT [4096];        // 8 KB
    __shared__ float  qsl[4][64];

    f4v acc[4];
#pragma unroll
    for (int vb = 0; vb < 4; ++vb) acc[vb] = f4v{0.f, 0.f, 0.f, 0.f};
    float qs = 0.f;

    const int li = lane & 15, g = lane >> 4;

    for (int ch = 0; ch < 4; ++ch) {
        const size_t r0 = base + ch * 64 + wid * 16;   // wave's 16 rows
        const float* kp = K + r0 * 64 + lane;
        const float* vp = V + r0 * 64 + lane;
        const float* qp = Q + r0 * 64 + lane;
        float kr[16], vr[16], qr[16];
#pragma unroll
        for (int i = 0; i < 16; ++i) kr[i] = kp[i * 64];
#pragma unroll
        for (int i = 0; i < 16; ++i) vr[i] = vp[i * 64];
#pragma unroll
        for (int i = 0; i < 16; ++i) qr[i] = qp[i * 64];

        // Q column-sum partials (lane = column)
#pragma unroll
        for (int i = 0; i < 16; ++i) qs += exp2f(qr[i] * CL);

        // K row softmax: args bounded (~|k|<6), no max subtraction needed
        float e[16];
#pragma unroll
        for (int i = 0; i < 16; ++i) e[i] = exp2f(kr[i] * CL);
        float rs[16];
#pragma unroll
        for (int i = 0; i < 16; ++i) rs[i] = wave_rowsum_to63(e[i]); // 16 indep VALU chains
        s8v kv0, kv1, vv0, vv1;
#pragma unroll
        for (int j = 0; j < 8; ++j) {
            const float r0i = __builtin_amdgcn_rcpf(rl63(rs[j]));
            const float r1i = __builtin_amdgcn_rcpf(rl63(rs[8 + j]));
            kv0[j] = (short)f2bf(e[j] * r0i);
            kv1[j] = (short)f2bf(e[8 + j] * r1i);
            vv0[j] = (short)f2bf(vr[j]);
            vv1[j] = (short)f2bf(vr[8 + j]);
        }

        __syncthreads();                 // prev chunk's MFMA reads done
        // wave's rows are granules 2wid (i=0..7) and 2wid+1 (i=8..15) of col=lane
        {
            const unsigned cbase = (unsigned)lane * 128u;
            const unsigned g0 = (unsigned)(((2 * wid)     ^ (lane & 7)) << 4);
            const unsigned g1 = (unsigned)(((2 * wid + 1) ^ (lane & 7)) << 4);
            *(s8v*)((char*)kkT + cbase + g0) = kv0;
            *(s8v*)((char*)kkT + cbase + g1) = kv1;
            *(s8v*)((char*)vT  + cbase + g0) = vv0;
            *(s8v*)((char*)vT  + cbase + g1) = vv1;
        }
        __syncthreads();

        // MFMA: wave owns tile-row cb=wid; K=64 -> 2 k-steps of 32
#pragma unroll
        for (int ks = 0; ks < 2; ++ks) {
            const int G  = ks * 4 + g;           // row granule (8 rows each)
            const int ca = wid * 16 + li;
            s8v a = *(const s8v*)((const char*)kkT + ca * 128 + ((G ^ (ca & 7)) << 4));
#pragma unroll
            for (int vb = 0; vb < 4; ++vb) {
                const int c0 = vb * 16 + li;
                s8v b = *(const s8v*)((const char*)vT + c0 * 128 + ((G ^ (c0 & 7)) << 4));
                acc[vb] = __builtin_amdgcn_mfma_f32_16x16x32_bf16(a, b, acc[vb], 0, 0, 0);
            }
        }
    }
    // write partial ctx tiles: D row = 4*g + r (+cb*16), col = li (+vb*16)
#pragma unroll
    for (int vb = 0; vb < 4; ++vb)
#pragma unroll
        for (int r = 0; r < 4; ++r)
            ctx_part[(size_t)blockIdx.x * 4096 +
                     (wid * 16 + g * 4 + r) * 64 + vb * 16 + li] = acc[vb][r];

    qsl[wid][lane] = qs;
    __syncthreads();
    if (tid < 64)
        qs_part[blockIdx.x * 64 + tid] =
            (qsl[0][tid] + qsl[1][tid]) + (qsl[2][tid] + qsl[3][tid]);
}

// K2: one block per column c. Reduce ctx partials AND Q column-sum partials,
// fold 1/colsum, emit ctx TRANSPOSED bf16: ctxfT[v][c].
__global__ __launch_bounds__(256) void k2(const float* __restrict__ ctx_part,
                                          const float* __restrict__ qs_part,
                                          ushort* __restrict__ ctxfT) {
    const int c = blockIdx.x;        // 64 blocks
    const int tid = threadIdx.x;
    const int v = tid & 63;
    const int g = tid >> 6;          // 0..3
    __shared__ float red[4][64];
    __shared__ float qred[4][64];
    float s = 0.f;
    for (int b = g; b < B1; b += 4) s += ctx_part[(size_t)b * 4096 + c * 64 + v];
    float q = 0.f;
    for (int b = tid; b < B1; b += 256) q += qs_part[b * 64 + c];
    red[g][v] = s;
    qred[g][v] = q;
    __syncthreads();
    if (tid < 64) {
        float t  = (red[0][v] + red[1][v]) + (red[2][v] + red[3][v]);
        float qv = (qred[0][v] + qred[1][v]) + (qred[2][v] + qred[3][v]);
        qv = dpp_red16(qv);
        qv += __shfl_xor(qv, 16);
        qv += __shfl_xor(qv, 32);
        ctxfT[v * 64 + c] = f2bf(t * __builtin_amdgcn_rcpf(qv));
    }
}

// K3: out[i][:] = exp2(Q[i][:]*CL) @ ctx'  via MFMA. A-frags straight from
// global Q (8 consecutive cols per lane); B-frags (ctx', 8KB) block-constant.
__global__ __launch_bounds__(256) void k3_out(const float* __restrict__ Q,
                                              const ushort* __restrict__ ctxfT,
                                              float* __restrict__ out) {
    const int tid  = threadIdx.x;
    const int lane = tid & 63;
    const int wid  = tid >> 6;      // 4 waves
    const int li = lane & 15, g = lane >> 4;

    s8v bfr[4][2];
#pragma unroll
    for (int vb = 0; vb < 4; ++vb)
#pragma unroll
        for (int ks = 0; ks < 2; ++ks)
            bfr[vb][ks] = *(const s8v*)((const char*)ctxfT +
                            2 * ((vb * 16 + li) * 64 + 32 * ks + 8 * g));

#pragma unroll
    for (int t = 0; t < 4; ++t) {   // fully unrolled: loads from all tiles in flight
        const int rb  = blockIdx.x * 256 + t * 64 + wid * 16;
        const int row = rb + li;
        const f4v* qp = (const f4v*)(Q + (size_t)row * 64);
        f4v q0 = qp[2 * g], q1 = qp[2 * g + 1];         // cols 8g..8g+7   (ks=0)
        f4v q2 = qp[8 + 2 * g], q3 = qp[8 + 2 * g + 1]; // cols 32+8g..+7  (ks=1)
        s8v a0, a1;
#pragma unroll
        for (int e = 0; e < 4; ++e) {
            a0[e]     = (short)f2bf(exp2f(q0[e] * CL));
            a0[e + 4] = (short)f2bf(exp2f(q1[e] * CL));
            a1[e]     = (short)f2bf(exp2f(q2[e] * CL));
            a1[e + 4] = (short)f2bf(exp2f(q3[e] * CL));
        }
#pragma unroll
        for (int vb = 0; vb < 4; ++vb) {
            f4v acc = {0.f, 0.f, 0.f, 0.f};
            acc = __builtin_amdgcn_mfma_f32_16x16x32_bf16(a0, bfr[vb][0], acc, 0, 0, 0);
            acc = __builtin_amdgcn_mfma_f32_16x16x32_bf16(a1, bfr[vb][1], acc, 0, 0, 0);
#pragma unroll
            for (int r = 0; r < 4; ++r)
                out[(size_t)(rb + g * 4 + r) * 64 + vb * 16 + li] = acc[r];
        }
    }
}

extern "C" void kernel_launch(void* const* d_in, const int* in_sizes, int n_in,
                              void* d_out, int out_size, void* d_ws, size_t ws_size,
                              hipStream_t stream) {
    const float* Q = (const float*)d_in[0];
    const float* K = (const float*)d_in[1];
    const float* V = (const float*)d_in[2];
    float* out = (float*)d_out;

    float* w = (float*)d_ws;
    size_t off = 0;
    float*  qs_part = w + off;              off += (size_t)B1 * 64;
    ushort* ctxfT   = (ushort*)(w + off);   off += 2048;   // 4096 bf16 = 8KB
    float* ctx_part;
    const size_t need = (off + (size_t)B1 * 4096) * sizeof(float);
    if (ws_size >= need) {
        ctx_part = w + off;
    } else {
        // 16.8 MB of partials live in d_out scratch (k3 fully overwrites later)
        ctx_part = out;
    }

    k1_stats<<<B1, 256, 0, stream>>>(Q, K, V, ctx_part, qs_part);
    k2<<<64, 256, 0, stream>>>(ctx_part, qs_part, ctxfT);
    k3_out<<<NROWS / 256, 256, 0, stream>>>(Q, ctxfT, out);
}

// Round 9
// 83.496 us; speedup vs baseline: 1.4927x; 1.4927x over previous
//
#include <hip/hip_runtime.h>
#include <hip/hip_bf16.h>

#define NROWS 262144
#define NB1 1024           // k1 blocks
#define RPB 256            // rows per k1 block (4 chunks of 64)
// exp(x*0.125) == exp2(x * 0.125*log2(e))
#define CL 0.18033688011112042f
#define PW 20              // padded panel width (ushorts): conflict-free u16 reads

typedef __attribute__((ext_vector_type(8))) short s8v;   // 8 bf16 (4 VGPRs)
typedef __attribute__((ext_vector_type(4))) short s4h;   // 4 bf16 (2 VGPRs)
typedef __attribute__((ext_vector_type(4))) float f4v;   // float4 / MFMA acc

__device__ __forceinline__ short f2bf(float x) {         // RNE float->bf16 bits
    unsigned u = __float_as_uint(x);
    u += 0x7FFF + ((u >> 16) & 1);
    return (short)(u >> 16);
}

// sum over each contiguous 16-lane group via DPP (VALU pipe only)
__device__ __forceinline__ float dpp_red16(float x) {
    int t;
    t = __builtin_amdgcn_update_dpp(0, __float_as_int(x), 0xB1,  0xF, 0xF, true); // quad xor1
    x += __int_as_float(t);
    t = __builtin_amdgcn_update_dpp(0, __float_as_int(x), 0x4E,  0xF, 0xF, true); // quad xor2
    x += __int_as_float(t);
    t = __builtin_amdgcn_update_dpp(0, __float_as_int(x), 0x141, 0xF, 0xF, true); // half_mirror
    x += __int_as_float(t);
    t = __builtin_amdgcn_update_dpp(0, __float_as_int(x), 0x140, 0xF, 0xF, true); // mirror
    x += __int_as_float(t);
    return x;
}

// K1: 256 rows/block, 4 waves, 4 chunks of 64 rows. float4 global loads
// (lane l -> row +(l>>4), cols 4*(l&15)..+3). Row-softmax via dpp_red16 over
// the 16-lane row group. bf16 packed row-major into padded 16-col panels;
// MFMA fragments read back as plain u16 column reads (2-way aliased = free).
// Computes ctx^T = V^T @ kk so D-frags give 4 consecutive v per lane ->
// dwordx4 stores. Q column-sums fused.
__global__ __launch_bounds__(256, 4) void k1_stats(const float* __restrict__ Q,
                                                   const float* __restrict__ K,
                                                   const float* __restrict__ V,
                                                   float* __restrict__ ctx_part,  // [NB1][c][v]
                                                   float* __restrict__ qs_part)   // [NB1][64]
{
    const int tid  = threadIdx.x;
    const int lane = tid & 63;
    const int wid  = tid >> 6;          // 4 waves
    const int m    = lane & 15;         // col-quad (cols 4m..4m+3)
    const int g    = lane >> 4;         // row-in-quad / k-group
    const size_t base = (size_t)blockIdx.x * RPB;

    __shared__ ushort kkP[4][64][PW];   // panel p = cols 16p..16p+15 (padded)
    __shared__ ushort vP [4][64][PW];
    __shared__ float  qsl[4][64];

    f4v acc[4];
#pragma unroll
    for (int va = 0; va < 4; ++va) acc[va] = f4v{0.f, 0.f, 0.f, 0.f};
    f4v qs4 = {0.f, 0.f, 0.f, 0.f};

    const f4v* K4 = (const f4v*)K;
    const f4v* V4 = (const f4v*)V;
    const f4v* Q4 = (const f4v*)Q;

    for (int ch = 0; ch < 4; ++ch) {
        const size_t r0 = base + ch * 64 + wid * 16;   // wave's 16 rows
        f4v k4[4], v4[4], q4[4];
#pragma unroll
        for (int i = 0; i < 4; ++i) k4[i] = K4[(r0 + i * 4 + g) * 16 + m];
#pragma unroll
        for (int i = 0; i < 4; ++i) v4[i] = V4[(r0 + i * 4 + g) * 16 + m];
#pragma unroll
        for (int i = 0; i < 4; ++i) q4[i] = Q4[(r0 + i * 4 + g) * 16 + m];

        // Q colsum partials (col 4m+c fixed per lane)
#pragma unroll
        for (int i = 0; i < 4; ++i) {
            qs4[0] += exp2f(q4[i][0] * CL); qs4[1] += exp2f(q4[i][1] * CL);
            qs4[2] += exp2f(q4[i][2] * CL); qs4[3] += exp2f(q4[i][3] * CL);
        }
        // K row softmax (args bounded, no max): row = 16-lane group
        f4v e4[4]; float rs[4];
#pragma unroll
        for (int i = 0; i < 4; ++i) {
            e4[i][0] = exp2f(k4[i][0] * CL); e4[i][1] = exp2f(k4[i][1] * CL);
            e4[i][2] = exp2f(k4[i][2] * CL); e4[i][3] = exp2f(k4[i][3] * CL);
        }
#pragma unroll
        for (int i = 0; i < 4; ++i)
            rs[i] = dpp_red16((e4[i][0] + e4[i][1]) + (e4[i][2] + e4[i][3]));
        s4h kp[4], vp4[4];
#pragma unroll
        for (int i = 0; i < 4; ++i) {
            const float inv = __builtin_amdgcn_rcpf(rs[i]);
            kp[i]  = s4h{f2bf(e4[i][0] * inv), f2bf(e4[i][1] * inv),
                         f2bf(e4[i][2] * inv), f2bf(e4[i][3] * inv)};
            vp4[i] = s4h{f2bf(v4[i][0]), f2bf(v4[i][1]),
                         f2bf(v4[i][2]), f2bf(v4[i][3])};
        }

        __syncthreads();                 // prev chunk's frag reads done
#pragma unroll
        for (int i = 0; i < 4; ++i) {
            const int lr = wid * 16 + i * 4 + g;      // local row
            *(s4h*)&kkP[m >> 2][lr][(m & 3) * 4] = kp[i];
            *(s4h*)&vP [m >> 2][lr][(m & 3) * 4] = vp4[i];
        }
        __syncthreads();

        // fragments via plain u16 column reads (row 32ks+8g+e, col m)
#pragma unroll
        for (int ks = 0; ks < 2; ++ks) {
            s8v bf;
#pragma unroll
            for (int e = 0; e < 8; ++e)
                bf[e] = (short)kkP[wid][32 * ks + 8 * g + e][m];
            s8v af[4];
#pragma unroll
            for (int va = 0; va < 4; ++va)
#pragma unroll
                for (int e = 0; e < 8; ++e)
                    af[va][e] = (short)vP[va][32 * ks + 8 * g + e][m];
#pragma unroll
            for (int va = 0; va < 4; ++va)
                acc[va] = __builtin_amdgcn_mfma_f32_16x16x32_bf16(af[va], bf, acc[va], 0, 0, 0);
        }
    }

    // D[v][c]: lane holds v = va*16 + 4g + r (consecutive), c = wid*16 + m
#pragma unroll
    for (int va = 0; va < 4; ++va)
        *(f4v*)&ctx_part[(size_t)blockIdx.x * 4096 +
                         (wid * 16 + m) * 64 + va * 16 + 4 * g] = acc[va];

    // Q colsum: combine the 4 row-groups sharing col-quad m
#pragma unroll
    for (int c = 0; c < 4; ++c) {
        qs4[c] += __shfl_xor(qs4[c], 16);
        qs4[c] += __shfl_xor(qs4[c], 32);
    }
    if (g == 0) *(f4v*)&qsl[wid][4 * m] = qs4;
    __syncthreads();
    if (tid < 64)
        qs_part[blockIdx.x * 64 + tid] =
            (qsl[0][tid] + qsl[1][tid]) + (qsl[2][tid] + qsl[3][tid]);
}

// K2: one block per column c. float4 reduce of ctx partials + Q colsum
// partials; fold 1/colsum; emit ctx' TRANSPOSED bf16: ctxfT[v][c].
__global__ __launch_bounds__(256) void k2(const float* __restrict__ ctx_part,
                                          const float* __restrict__ qs_part,
                                          ushort* __restrict__ ctxfT) {
    const int c = blockIdx.x;        // 64 blocks
    const int tid = threadIdx.x;
    const int bg = tid >> 4, vq = tid & 15;
    __shared__ f4v  red[16][16];
    __shared__ float qred[4][64];
    f4v s = {0.f, 0.f, 0.f, 0.f};
    for (int b = bg; b < NB1; b += 16)
        s += *(const f4v*)&ctx_part[(size_t)b * 4096 + c * 64 + vq * 4];
    float q = 0.f;
    for (int b = tid; b < NB1; b += 256) q += qs_part[b * 64 + c];
    red[bg][vq] = s;
    qred[tid >> 6][tid & 63] = q;
    __syncthreads();
    if (tid < 64) {
        float t = 0.f;
#pragma unroll
        for (int b = 0; b < 16; ++b) t += red[b][tid >> 2][tid & 3];
        float qv = (qred[0][tid] + qred[1][tid]) + (qred[2][tid] + qred[3][tid]);
        qv = dpp_red16(qv);
        qv += __shfl_xor(qv, 16);
        qv += __shfl_xor(qv, 32);
        ctxfT[tid * 64 + c] = (ushort)f2bf(t * __builtin_amdgcn_rcpf(qv));
    }
}

// K3: out = q~ @ ctx' via MFMA with swapped operands (A=ctx'^T frags, B=q~
// frags) so D = out^T frags give 4 consecutive out cols/lane -> dwordx4.
__global__ __launch_bounds__(256) void k3_out(const float* __restrict__ Q,
                                              const ushort* __restrict__ ctxfT,
                                              float* __restrict__ out) {
    const int tid  = threadIdx.x;
    const int lane = tid & 63;
    const int wid  = tid >> 6;      // 4 waves
    const int li = lane & 15, g = lane >> 4;

    s8v ct[4][2];                   // A frags: ctxfT[va*16+li][32ks+8g .. +7]
#pragma unroll
    for (int va = 0; va < 4; ++va)
#pragma unroll
        for (int ks = 0; ks < 2; ++ks)
            ct[va][ks] = *(const s8v*)((const char*)ctxfT +
                            2 * ((va * 16 + li) * 64 + 32 * ks + 8 * g));

#pragma unroll
    for (int t = 0; t < 4; ++t) {
        const int rb  = blockIdx.x * 256 + t * 64 + wid * 16;
        const int row = rb + li;
        const f4v* qp = (const f4v*)(Q + (size_t)row * 64);
        f4v q0 = qp[2 * g], q1 = qp[2 * g + 1];          // cols 8g..+7   (ks=0)
        f4v q2 = qp[8 + 2 * g], q3 = qp[8 + 2 * g + 1];  // cols 32+8g..+7 (ks=1)
        s8v b0, b1;                 // B frags: q~[row][32ks+8g .. +7]
#pragma unroll
        for (int e = 0; e < 4; ++e) {
            b0[e]     = f2bf(exp2f(q0[e] * CL));
            b0[e + 4] = f2bf(exp2f(q1[e] * CL));
            b1[e]     = f2bf(exp2f(q2[e] * CL));
            b1[e + 4] = f2bf(exp2f(q3[e] * CL));
        }
#pragma unroll
        for (int va = 0; va < 4; ++va) {
            f4v a = {0.f, 0.f, 0.f, 0.f};
            a = __builtin_amdgcn_mfma_f32_16x16x32_bf16(ct[va][0], b0, a, 0, 0, 0);
            a = __builtin_amdgcn_mfma_f32_16x16x32_bf16(ct[va][1], b1, a, 0, 0, 0);
            *(f4v*)&out[(size_t)row * 64 + va * 16 + 4 * g] = a;   // 4 consecutive v
        }
    }
}

extern "C" void kernel_launch(void* const* d_in, const int* in_sizes, int n_in,
                              void* d_out, int out_size, void* d_ws, size_t ws_size,
                              hipStream_t stream) {
    const float* Q = (const float*)d_in[0];
    const float* K = (const float*)d_in[1];
    const float* V = (const float*)d_in[2];
    float* out = (float*)d_out;

    float* w = (float*)d_ws;
    size_t off = 0;
    float*  qs_part = w + off;              off += (size_t)NB1 * 64;
    ushort* ctxfT   = (ushort*)(w + off);   off += 2048;   // 4096 bf16 = 8KB
    float* ctx_part;
    const size_t need = (off + (size_t)NB1 * 4096) * sizeof(float);
    if (ws_size >= need) {
        ctx_part = w + off;
    } else {
        // 16.8 MB of partials live in d_out scratch (k3 fully overwrites later)
        ctx_part = out;
    }

    k1_stats<<<NB1, 256, 0, stream>>>(Q, K, V, ctx_part, qs_part);
    k2<<<64, 256, 0, stream>>>(ctx_part, qs_part, ctxfT);
    k3_out<<<NROWS / 256, 256, 0, stream>>>(Q, ctxfT, out);
}